// Round 16
// baseline (60.913 us; speedup 1.0000x reference)
//
#include <hip/hip_runtime.h>
#include <hip/hip_bf16.h>
#include <hip/hip_fp8.h>

#define B_ 8192
#define C_ 10000
#define D_ 128
#define CPAD 10112      // 158 * 64
#define NPADC 112       // CPAD - C_
#define NT_TOT 158      // 64-col tiles
#define NSTRIP 16
#define STRIPW 10       // strips 0..14 -> 10 tiles, strip 15 -> 8 (both even)
#define UPD_BLOCKS 2528 // CPAD/4
#define CVAL_BLOCKS 2048// B_/4

typedef float f32x4 __attribute__((ext_vector_type(4)));
typedef int   i32x8 __attribute__((ext_vector_type(8)));

typedef const __attribute__((address_space(1))) uint32_t gu32;
typedef __attribute__((address_space(3))) uint32_t lu32;

// ---------------- ws layout (float offsets) ----------------
// counts    : [0, 10240)
// sumx      : [10240, 1290240)
// git_row   : [1290240, 1298432)
// xnorm     : [1298432, 1306624)
// cent_val  : [1306624, 1314816)
// cnorm     : [1314816, 1325056)   (CPAD, pad = 0)
// x_fp8     : byte 5,300,224  (8192 x 128 = 1 MB)
// c_fp8     : byte 7,397,376  (CPAD x 128, pad rows zero)

__global__ void zero_ws(float4* __restrict__ ws, float* __restrict__ out) {
    int idx = blockIdx.x * 256 + threadIdx.x;
    if (idx < 324608) ws[idx] = float4{0.f, 0.f, 0.f, 0.f};
    if (idx == 0) { out[0] = 0.f; out[1] = 0.f; }
}

// Fused: segment-sum atomics + fp8 cast + xnorm (single pass over x).
__global__ void scatter_prep(const float* __restrict__ x, const int* __restrict__ labels,
                             float* __restrict__ counts, float* __restrict__ sumx,
                             float* __restrict__ xnorm, unsigned char* __restrict__ xb8) {
    int tid = threadIdx.x;
    int w = tid >> 6, lane = tid & 63;
    int i = blockIdx.x * 4 + w;
    int l = labels[i];
    float2 v = *(const float2*)&x[i * D_ + lane * 2];
    atomicAdd(&sumx[l * D_ + lane * 2], v.x);
    atomicAdd(&sumx[l * D_ + lane * 2 + 1], v.y);
    if (lane == 0) atomicAdd(&counts[l], 1.0f);
    __hip_fp8_e4m3 a(v.x), b(v.y);
    unsigned short pk = (unsigned short)a.__x | ((unsigned short)b.__x << 8);
    *(unsigned short*)&xb8[i * D_ + lane * 2] = pk;
    float s = v.x * v.x + v.y * v.y;
    #pragma unroll
    for (int m = 1; m < 64; m <<= 1) s += __shfl_xor(s, m);
    if (lane == 0) xnorm[i] = s;
}

__global__ void upd_cvals(const float* __restrict__ centers, const float* __restrict__ counts,
                          const float* __restrict__ sumx, float* __restrict__ cnorm,
                          unsigned char* __restrict__ cb8, const float* __restrict__ lr,
                          const float* __restrict__ x, const int* __restrict__ labels,
                          float* __restrict__ cent_val) {
    int tid = threadIdx.x;
    int w = tid >> 6, lane = tid & 63;
    int bid = blockIdx.x;
    float lrv = lr[0];

    if (bid < UPD_BLOCKS) {
        int c = bid * 4 + w;
        if (c >= C_) {
            *(unsigned short*)&cb8[c * D_ + lane * 2] = 0;
            if (lane == 0) cnorm[c] = 0.0f;
            return;
        }
        float cnt = counts[c];
        float2 cv = *(const float2*)&centers[c * D_ + lane * 2];
        float2 sx = *(const float2*)&sumx[c * D_ + lane * 2];
        float inv = 1.0f / (1.0f + cnt);
        float nx = cv.x - lrv * (cnt * cv.x - sx.x) * inv;
        float ny = cv.y - lrv * (cnt * cv.y - sx.y) * inv;
        __hip_fp8_e4m3 a(nx), b(ny);
        unsigned short pk = (unsigned short)a.__x | ((unsigned short)b.__x << 8);
        *(unsigned short*)&cb8[c * D_ + lane * 2] = pk;
        float s = nx * nx + ny * ny;
        #pragma unroll
        for (int m = 1; m < 64; m <<= 1) s += __shfl_xor(s, m);
        if (lane == 0) cnorm[c] = s;
    } else {
        int i = (bid - UPD_BLOCKS) * 4 + w;
        int l = labels[i];
        float cnt = counts[l];
        float inv = 1.0f / (1.0f + cnt);
        float2 a  = *(const float2*)&x[i * D_ + lane * 2];
        float2 cv = *(const float2*)&centers[l * D_ + lane * 2];
        float2 sx = *(const float2*)&sumx[l * D_ + lane * 2];
        float nx = cv.x - lrv * (cnt * cv.x - sx.x) * inv;
        float ny = cv.y - lrv * (cnt * cv.y - sx.y) * inv;
        float dx = a.x - nx, dy = a.y - ny;
        float s = dx * dx + dy * dy;
        #pragma unroll
        for (int m = 1; m < 64; m <<= 1) s += __shfl_xor(s, m);
        if (lane == 0) cent_val[i] = s;
    }
}

// MX-FP8 GEMM + git, super-tiled: 3-ring of 16KB buffers, each = 2 consecutive
// 64-col tiles (contiguous rows of c_fp8). ONE barrier + ONE counted vmcnt per
// super-tile (4x fewer sync events than R15); stage(s+2) issued AFTER the
// barrier (prior readers of that ring slot provably done -> WAR-safe).
__global__ void __launch_bounds__(256, 2)
gemm_git(const unsigned char* __restrict__ xb8, const unsigned char* __restrict__ cb8,
         const float* __restrict__ xnorm, const float* __restrict__ cnorm,
         float* __restrict__ git_row) {
    __shared__ char ldsB[3][16384];   // 128 B-rows x 128B fp8, XOR-swizzled
    __shared__ float cnLDS[STRIPW * 64];

    int tid = threadIdx.x;
    int w = tid >> 6, lane = tid & 63;
    int lr_ = lane & 15, lg = lane >> 4;
    int bm = blockIdx.x;              // 0..31
    int strip = blockIdx.y;           // 0..15
    int row0 = bm * 256 + w * 64;
    int bn0 = strip * STRIPW;
    int nt = (strip == NSTRIP - 1) ? (NT_TOT - bn0) : STRIPW;
    int ns = nt >> 1;                 // super-tiles (nt is even: 10 or 8)

    // A fragments: lane holds row (row0+f*16+lr_), k-bytes [lg*32, +32); pinned.
    i32x8 af[4];
    #pragma unroll
    for (int f = 0; f < 4; f++) {
        const uint4* pa = (const uint4*)(xb8 + (size_t)(row0 + f * 16 + lr_) * 128 + lg * 32);
        uint4 u0 = pa[0], u1 = pa[1];
        asm volatile("" : "+v"(u0.x), "+v"(u0.y), "+v"(u0.z), "+v"(u0.w),
                          "+v"(u1.x), "+v"(u1.y), "+v"(u1.z), "+v"(u1.w));
        af[f] = i32x8{(int)u0.x, (int)u0.y, (int)u0.z, (int)u0.w,
                      (int)u1.x, (int)u1.y, (int)u1.z, (int)u1.w};
    }

    float xn1[4][4];
    #pragma unroll
    for (int fm = 0; fm < 4; fm++)
        #pragma unroll
        for (int r = 0; r < 4; r++) {
            float v = 1.0f + xnorm[row0 + fm * 16 + lg * 4 + r];
            asm volatile("" : "+v"(v));
            xn1[fm][r] = v;
        }

    float gitsum[4][4] = {};

    // stage a 16KB super-tile: 1024 16B-slots; 256 threads cover 4 each.
    // slot idx -> row = idx>>3 (0..127), ch = idx&7; src chunk = ch ^ (row&7).
    const char* gB = (const char*)cb8;
    size_t goff[4];
    #pragma unroll
    for (int p = 0; p < 4; p++) {
        int idx = tid + p * 256;
        int sr = idx >> 3, sc = (idx & 7) ^ (sr & 7);
        goff[p] = (size_t)sr * 128 + sc * 16;
    }

    auto stage = [&](int s, int buf) {
        const char* base = gB + (size_t)(bn0 + 2 * s) * 64 * 128;  // 128 rows x 128B
        #pragma unroll
        for (int p = 0; p < 4; p++)
            __builtin_amdgcn_global_load_lds((gu32*)(base + goff[p]),
                                             (lu32*)&ldsB[buf][(tid + p * 256) * 16], 16, 0, 0);
    };

    // prologue: cnorm -> LDS, stage supers 0 and 1; single full drain.
    for (int i = tid; i < nt * 64; i += 256) cnLDS[i] = cnorm[bn0 * 64 + i];
    stage(0, 0);
    if (ns > 1) stage(1, 1);
    __syncthreads();

    for (int s = 0; s < ns; ++s) {
        int bc = s % 3;

        // stage(s) landed; stage(s+1)'s 4 loads may stay in flight.
        if (s + 1 < ns) asm volatile("s_waitcnt vmcnt(4)" ::: "memory");
        else            asm volatile("s_waitcnt vmcnt(0)" ::: "memory");
        __builtin_amdgcn_sched_barrier(0);
        __builtin_amdgcn_s_barrier();     // ONE barrier per super-tile
        __builtin_amdgcn_sched_barrier(0);

        // issue next-next stage AFTER the barrier (ring slot's readers done)
        if (s + 2 < ns) stage(s + 2, (s + 2) % 3);

        #pragma unroll
        for (int h = 0; h < 2; ++h) {
            int t = 2 * s + h;
            float cn[4];
            #pragma unroll
            for (int fn = 0; fn < 4; fn++) cn[fn] = cnLDS[t * 64 + fn * 16 + lr_];

            // B fragments: LDS row = h*64 + fn*16 + lr_ ; (row&7) == (lr_&7)
            i32x8 bfk[4];
            int r7 = lr_ & 7;
            #pragma unroll
            for (int fn = 0; fn < 4; fn++) {
                const char* rowp = &ldsB[bc][(h * 64 + fn * 16 + lr_) * 128];
                uint4 q0 = *(const uint4*)(rowp + (((lg * 2)     ^ r7) * 16));
                uint4 q1 = *(const uint4*)(rowp + (((lg * 2 + 1) ^ r7) * 16));
                bfk[fn] = i32x8{(int)q0.x, (int)q0.y, (int)q0.z, (int)q0.w,
                                (int)q1.x, (int)q1.y, (int)q1.z, (int)q1.w};
            }

            f32x4 acc[4][4] = {};
            __builtin_amdgcn_s_setprio(1);
            #pragma unroll
            for (int fm = 0; fm < 4; fm++)
                #pragma unroll
                for (int fn = 0; fn < 4; fn++)
                    acc[fm][fn] = __builtin_amdgcn_mfma_scale_f32_16x16x128_f8f6f4(
                        af[fm], bfk[fn], acc[fm][fn],
                        0, 0,             // cbsz=fp8(e4m3), blgp=fp8(e4m3)
                        0, 0x7F,          // scale_a opsel, scale_a (e8m0 1.0)
                        0, 0x7F);         // scale_b opsel, scale_b
            __builtin_amdgcn_s_setprio(0);

            #pragma unroll
            for (int fm = 0; fm < 4; fm++)
                #pragma unroll
                for (int r = 0; r < 4; r++) {
                    float base = xn1[fm][r];
                    #pragma unroll
                    for (int fp = 0; fp < 4; fp += 2) {
                        float u = base + cn[fp]     - 2.0f * acc[fm][fp][r];
                        float v = base + cn[fp + 1] - 2.0f * acc[fm][fp + 1][r];
                        gitsum[fm][r] += (u + v) * __builtin_amdgcn_rcpf(u * v);
                    }
                }
        }
        // no trailing barrier: next iteration's barrier protects the ring
    }

    #pragma unroll
    for (int fm = 0; fm < 4; fm++)
        #pragma unroll
        for (int r = 0; r < 4; r++) {
            float s = gitsum[fm][r];
            s += __shfl_xor(s, 1); s += __shfl_xor(s, 2);
            s += __shfl_xor(s, 4); s += __shfl_xor(s, 8);
            if (lr_ == 0) atomicAdd(&git_row[row0 + fm * 16 + lg * 4 + r], s);
        }
}

__global__ void final_reduce(const float* __restrict__ cent_val, const float* __restrict__ git_row,
                             const float* __restrict__ xnorm, float* __restrict__ out) {
    int tid = threadIdx.x;
    int i = blockIdx.x * 256 + tid;
    float c = cent_val[i];
    float cl = fminf(fmaxf(c, 1e-12f), 1e12f);
    float g = git_row[i] - 1.0f / (1.0f + c) - (float)NPADC / (1.0f + xnorm[i]);
    float gl = fminf(fmaxf(g, 1e-12f), 1e12f);
    #pragma unroll
    for (int m = 1; m < 64; m <<= 1) { cl += __shfl_xor(cl, m); gl += __shfl_xor(gl, m); }
    __shared__ float scl[4], sgl[4];
    if ((tid & 63) == 0) { scl[tid >> 6] = cl; sgl[tid >> 6] = gl; }
    __syncthreads();
    if (tid == 0) {
        float a = scl[0] + scl[1] + scl[2] + scl[3];
        float b = sgl[0] + sgl[1] + sgl[2] + sgl[3];
        atomicAdd(&out[0], a / (float)B_);
        atomicAdd(&out[1], b / (float)B_);
    }
}

extern "C" void kernel_launch(void* const* d_in, const int* in_sizes, int n_in,
                              void* d_out, int out_size, void* d_ws, size_t ws_size,
                              hipStream_t stream) {
    const float* x       = (const float*)d_in[0];
    const int*   labels  = (const int*)d_in[1];
    const float* centers = (const float*)d_in[2];
    const float* lr      = (const float*)d_in[3];

    float* ws       = (float*)d_ws;
    float* counts   = ws;
    float* sumx     = ws + 10240;
    float* git_row  = ws + 1290240;
    float* xnorm    = ws + 1298432;
    float* cent_val = ws + 1306624;
    float* cnorm    = ws + 1314816;
    unsigned char* xb8 = (unsigned char*)d_ws + 5300224;
    unsigned char* cb8 = (unsigned char*)d_ws + 7397376;
    float* out = (float*)d_out;

    zero_ws<<<1268, 256, 0, stream>>>((float4*)d_ws, out);
    scatter_prep<<<B_ / 4, 256, 0, stream>>>(x, labels, counts, sumx, xnorm, xb8);
    upd_cvals<<<UPD_BLOCKS + CVAL_BLOCKS, 256, 0, stream>>>(centers, counts, sumx, cnorm, cb8, lr,
                                                            x, labels, cent_val);
    gemm_git<<<dim3(32, NSTRIP), 256, 0, stream>>>(xb8, cb8, xnorm, cnorm, git_row);
    final_reduce<<<32, 256, 0, stream>>>(cent_val, git_row, xnorm, out);
}